// Round 1
// baseline (4161.209 us; speedup 1.0000x reference)
//
#include <hip/hip_runtime.h>
#include <math.h>

// Problem constants (B, N, D) = (32, 128, 128)
#define BATCH   32
#define NN      128
#define DD      128
#define APITCH  129   // adj row pitch (floats) — +1 pad to break bank alignment
#define XPITCH  132   // x   row pitch (floats) — keeps float4 alignment (132%4==0)
#define NT      512   // threads per block (8 waves)

// LDS layout (dynamic):
//   adj  : [128][129] fp32   = 16512 floats
//   xbuf : [128][132] fp32   = 16896 floats
//   prob : [128]
//   dinv : [128]
// total = 33664 floats = 134656 bytes  (needs opt-in > 64KB dynamic LDS)

__global__ __launch_bounds__(NT, 1)
void gcn_gen_kernel(const float* __restrict__ xin,
                    const float* __restrict__ W,
                    float* __restrict__ out) {
    extern __shared__ float smem[];
    float* adj  = smem;                       // [NN][APITCH]
    float* xbuf = smem + NN * APITCH;         // [NN][XPITCH]
    float* prob = xbuf + NN * XPITCH;         // [NN]
    float* dinv = prob + NN;                  // [NN]

    const int b  = blockIdx.x;
    const int t  = threadIdx.x;
    const int tc  = t & 15;     // col group: cols c0..c0+7
    const int trg = t >> 4;     // row group: rows r0..r0+3
    const int c0 = tc * 8;
    const int r0 = trg * 4;

    const float* xin_b = xin + (size_t)b * NN * DD;
    float*       out_b = out + (size_t)b * NN * NN;

    // ---------------- init ----------------
    // zero adj (including pad columns)
    for (int e = t; e < NN * APITCH; e += NT) adj[e] = 0.0f;

    // load x_in -> xbuf (coalesced float4)
    {
        const float4* src = (const float4*)xin_b;
        #pragma unroll
        for (int v = 0; v < (NN * DD / 4) / NT; ++v) {
            int idx = v * NT + t;           // float4 index
            float4 f = src[idx];
            int e = idx * 4;
            int r = e >> 7;                 // /128
            int c = e & 127;
            *(float4*)&xbuf[r * XPITCH + c] = f;
        }
    }
    __syncthreads();
    if (t < NN) {
        adj[t * (APITCH + 1)] = 1.0f;       // adj = I
        out_b[t * (NN + 1)]   = 1.0f;       // output diagonal (never overwritten)
    }
    __syncthreads();

    // ---------------- x = relu(x_in @ W) ----------------
    {
        float acc[4][8];
        #pragma unroll
        for (int k = 0; k < 4; ++k)
            #pragma unroll
            for (int c = 0; c < 8; ++c) acc[k][c] = 0.0f;

        #pragma unroll 4
        for (int j = 0; j < DD; ++j) {
            float a0 = xbuf[(r0 + 0) * XPITCH + j];
            float a1 = xbuf[(r0 + 1) * XPITCH + j];
            float a2 = xbuf[(r0 + 2) * XPITCH + j];
            float a3 = xbuf[(r0 + 3) * XPITCH + j];
            float4 w0 = *(const float4*)&W[j * DD + c0];
            float4 w1 = *(const float4*)&W[j * DD + c0 + 4];
            float wv[8] = {w0.x, w0.y, w0.z, w0.w, w1.x, w1.y, w1.z, w1.w};
            float av[4] = {a0, a1, a2, a3};
            #pragma unroll
            for (int k = 0; k < 4; ++k)
                #pragma unroll
                for (int c = 0; c < 8; ++c)
                    acc[k][c] = fmaf(av[k], wv[c], acc[k][c]);
        }
        __syncthreads();
        #pragma unroll
        for (int k = 0; k < 4; ++k) {
            float4 o0 = {fmaxf(acc[k][0], 0.f), fmaxf(acc[k][1], 0.f),
                         fmaxf(acc[k][2], 0.f), fmaxf(acc[k][3], 0.f)};
            float4 o1 = {fmaxf(acc[k][4], 0.f), fmaxf(acc[k][5], 0.f),
                         fmaxf(acc[k][6], 0.f), fmaxf(acc[k][7], 0.f)};
            *(float4*)&xbuf[(r0 + k) * XPITCH + c0]     = o0;
            *(float4*)&xbuf[(r0 + k) * XPITCH + c0 + 4] = o1;
        }
        __syncthreads();
    }

    // ---------------- scan over i = 1..127 ----------------
    for (int i = 1; i < NN; ++i) {
        // --- prob[j] = dot(x[j], x[i]), masked j<i ---
        {
            int j = t >> 2, q = t & 3;
            const float* xr = &xbuf[j * XPITCH + q * 32];
            const float* xi = &xbuf[i * XPITCH + q * 32];
            float s = 0.0f;
            #pragma unroll
            for (int d = 0; d < 32; ++d) s = fmaf(xr[d], xi[d], s);
            s += __shfl_down(s, 2, 4);
            s += __shfl_down(s, 1, 4);
            if (q == 0) prob[j] = (j < i) ? s : 0.0f;
        }
        __syncthreads();

        // --- update adj row/col i (raw prob) and output ---
        if (t < i) {
            float p = prob[t];
            adj[i * APITCH + t] = p;
            adj[t * APITCH + i] = p;
            out_b[i * NN + t] = p;
            out_b[t * NN + i] = p;
        }
        __syncthreads();

        // --- deg / dinv ---
        {
            int j = t >> 2, q = t & 3;
            const float* ar = &adj[j * APITCH + q * 32];
            float s = 0.0f;
            #pragma unroll
            for (int d = 0; d < 32; ++d) s += ar[d];
            s += __shfl_down(s, 2, 4);
            s += __shfl_down(s, 1, 4);
            if (q == 0) dinv[j] = 1.0f / sqrtf(s);
        }
        __syncthreads();

        // --- normalize adj in place ---
        {
            int r = t >> 2, q = t & 3;
            float dr = dinv[r];
            float* ar = &adj[r * APITCH + q * 32];
            const float* dc = &dinv[q * 32];
            #pragma unroll
            for (int d = 0; d < 32; ++d) ar[d] = ar[d] * dr * dc[d];
        }
        __syncthreads();

        // --- y = adj @ x  (into registers) ---
        float acc[4][8];
        #pragma unroll
        for (int k = 0; k < 4; ++k)
            #pragma unroll
            for (int c = 0; c < 8; ++c) acc[k][c] = 0.0f;

        #pragma unroll 4
        for (int j = 0; j < NN; ++j) {
            float a0 = adj[(r0 + 0) * APITCH + j];
            float a1 = adj[(r0 + 1) * APITCH + j];
            float a2 = adj[(r0 + 2) * APITCH + j];
            float a3 = adj[(r0 + 3) * APITCH + j];
            float4 b0 = *(const float4*)&xbuf[j * XPITCH + c0];
            float4 b1 = *(const float4*)&xbuf[j * XPITCH + c0 + 4];
            float bv[8] = {b0.x, b0.y, b0.z, b0.w, b1.x, b1.y, b1.z, b1.w};
            float av[4] = {a0, a1, a2, a3};
            #pragma unroll
            for (int k = 0; k < 4; ++k)
                #pragma unroll
                for (int c = 0; c < 8; ++c)
                    acc[k][c] = fmaf(av[k], bv[c], acc[k][c]);
        }
        __syncthreads();

        // --- write y into xbuf (x is dead now) ---
        #pragma unroll
        for (int k = 0; k < 4; ++k) {
            float4 o0 = {acc[k][0], acc[k][1], acc[k][2], acc[k][3]};
            float4 o1 = {acc[k][4], acc[k][5], acc[k][6], acc[k][7]};
            *(float4*)&xbuf[(r0 + k) * XPITCH + c0]     = o0;
            *(float4*)&xbuf[(r0 + k) * XPITCH + c0 + 4] = o1;
        }
        __syncthreads();

        // --- x_new = relu(y @ W) ---
        float acc2[4][8];
        #pragma unroll
        for (int k = 0; k < 4; ++k)
            #pragma unroll
            for (int c = 0; c < 8; ++c) acc2[k][c] = 0.0f;

        #pragma unroll 4
        for (int j = 0; j < DD; ++j) {
            float a0 = xbuf[(r0 + 0) * XPITCH + j];
            float a1 = xbuf[(r0 + 1) * XPITCH + j];
            float a2 = xbuf[(r0 + 2) * XPITCH + j];
            float a3 = xbuf[(r0 + 3) * XPITCH + j];
            float4 w0 = *(const float4*)&W[j * DD + c0];
            float4 w1 = *(const float4*)&W[j * DD + c0 + 4];
            float wv[8] = {w0.x, w0.y, w0.z, w0.w, w1.x, w1.y, w1.z, w1.w};
            float av[4] = {a0, a1, a2, a3};
            #pragma unroll
            for (int k = 0; k < 4; ++k)
                #pragma unroll
                for (int c = 0; c < 8; ++c)
                    acc2[k][c] = fmaf(av[k], wv[c], acc2[k][c]);
        }
        __syncthreads();

        // --- write x_new ---
        #pragma unroll
        for (int k = 0; k < 4; ++k) {
            float4 o0 = {fmaxf(acc2[k][0], 0.f), fmaxf(acc2[k][1], 0.f),
                         fmaxf(acc2[k][2], 0.f), fmaxf(acc2[k][3], 0.f)};
            float4 o1 = {fmaxf(acc2[k][4], 0.f), fmaxf(acc2[k][5], 0.f),
                         fmaxf(acc2[k][6], 0.f), fmaxf(acc2[k][7], 0.f)};
            *(float4*)&xbuf[(r0 + k) * XPITCH + c0]     = o0;
            *(float4*)&xbuf[(r0 + k) * XPITCH + c0 + 4] = o1;
        }
        __syncthreads();
    }
}

extern "C" void kernel_launch(void* const* d_in, const int* in_sizes, int n_in,
                              void* d_out, int out_size, void* d_ws, size_t ws_size,
                              hipStream_t stream) {
    const float* x = (const float*)d_in[0];   // (32,128,128)
    const float* W = (const float*)d_in[1];   // (128,128)
    float* out = (float*)d_out;               // (32,128,128)

    const size_t shmem = (size_t)(NN * APITCH + NN * XPITCH + NN + NN) * sizeof(float);
    // Opt-in to >64KB dynamic LDS (idempotent; safe under graph capture — not a stream op)
    hipFuncSetAttribute((const void*)gcn_gen_kernel,
                        hipFuncAttributeMaxDynamicSharedMemorySize, (int)shmem);

    gcn_gen_kernel<<<dim3(BATCH), dim3(NT), shmem, stream>>>(x, W, out);
}